// Round 1
// baseline (187.119 us; speedup 1.0000x reference)
//
#include <hip/hip_runtime.h>
#include <hip/hip_cooperative_groups.h>
#include <math.h>

namespace cg = cooperative_groups;

// Problem constants
#define TGT 560
#define B_ 2
#define K_ 1600
#define D_ 1024
#define C_ 256
#define N_ 32
#define P_ 40
#define KC_ 32      // k-chunks
#define KCHUNK 50   // K_/KC_

// ws layout (float offsets)
#define OFF_IFN ((size_t)0)                      // B*K = 3200 inverse feat norms
#define OFF_IEN (OFF_IFN + (size_t)B_ * K_)      // C = 256 inverse emb norms
#define OFF_BOXW (OFF_IEN + (size_t)C_)          // B*N*80 (wy*invcnt | wx)
#define OFF_G   ((size_t)16384)                  // B*N*D = 65536 floats (reduced g)
#define OFF_GP  (OFF_G + (size_t)B_ * N_ * D_)   // partials: [b][kc][dt][n][256] = 2M floats (8 MB)

// Single cooperative kernel: 256 blocks x 256 threads, 4 phases, 3 grid syncs.
// Replaces 3 launches (saves ~2x launch overhead) and kills kB's 2.1M global atomics.
__global__ __launch_bounds__(256) void fused(const float* __restrict__ feats,
                                             const float* __restrict__ emb,
                                             const int* __restrict__ boxes,
                                             float* __restrict__ ws,
                                             float* __restrict__ out) {
    __shared__ __align__(16) float smem[4224];   // 16.5 KB, reused across phases
    const int bid = blockIdx.x;
    const int t = threadIdx.x;
    const int lane = t & 63;
    const int wv = t >> 6;
    cg::grid_group grid = cg::this_grid();

    // ---- Phase 1: inverse row norms (wave-per-row) + per-box separable bicubic weights ----
    {
        const int gw = bid * 4 + wv;             // global wave id, 1024 waves
        for (int r = gw; r < B_ * K_ + C_; r += 1024) {
            const float* src;
            float* dst;
            if (r < B_ * K_) { src = feats + (size_t)r * D_; dst = ws + OFF_IFN + r; }
            else             { src = emb + (size_t)(r - B_ * K_) * D_; dst = ws + OFF_IEN + (r - B_ * K_); }
            const float4* p4 = (const float4*)src;
            float s = 0.f;
            #pragma unroll
            for (int i = 0; i < 4; ++i) {
                float4 v = p4[lane + 64 * i];
                s += v.x * v.x + v.y * v.y + v.z * v.z + v.w * v.w;
            }
            #pragma unroll
            for (int off = 32; off > 0; off >>= 1) s += __shfl_down(s, off, 64);
            if (lane == 0) *dst = 1.0f / sqrtf(s);   // eps fold: rel err ~1e-11
        }
        if (bid < 16) {                          // 16 blocks x 4 waves = 64 box tasks
            for (int i = t; i < 320; i += 256) smem[i] = 0.f;
            __syncthreads();
            const int bn = bid * 4 + wv;
            const int* bx = boxes + bn * 4;
            const int xmin = bx[0], ymin = bx[1], xmax = bx[2], ymax = bx[3];
            float* wsl = smem + wv * 80;
            #pragma unroll
            for (int axis = 0; axis < 2; ++axis) {
                const int lo = axis ? xmin : ymin;
                const int hi = (axis ? xmax : ymax) - 2;   // inclusive
                for (int h = lo + lane; h <= hi; h += 64) {
                    float sf = ((float)h + 0.5f) * (1.0f / 14.0f) - 0.5f;
                    int jf = (int)floorf(sf);
                    float w[4];
                    float norm = 0.f;
                    #pragma unroll
                    for (int dj = -1; dj <= 2; ++dj) {
                        int j = jf + dj;
                        float x = fabsf(sf - (float)j);
                        float wvv = ((1.5f * x - 2.5f) * x) * x + 1.f;                // |x|<1 (Keys a=-0.5)
                        if (x >= 1.f) wvv = ((-0.5f * x + 2.5f) * x - 4.f) * x + 2.f; // 1<=|x|<2
                        if (x >= 2.f) wvv = 0.f;
                        if (j < 0 || j >= P_) wvv = 0.f;   // edge tap -> renorm below
                        w[dj + 1] = wvv;
                        norm += wvv;
                    }
                    float inv = 1.0f / norm;
                    #pragma unroll
                    for (int dj = 0; dj < 4; ++dj) {
                        int j = jf - 1 + dj;
                        if (w[dj] != 0.f) atomicAdd(&wsl[axis * P_ + j], w[dj] * inv);
                    }
                }
            }
            __syncthreads();
            const float invcnt = 1.0f / ((float)(ymax - 1 - ymin) * (float)(xmax - 1 - xmin));
            for (int i = lane; i < 80; i += 64) {
                float val = smem[wv * 80 + i];
                if (i < P_) val *= invcnt;               // fold 1/count into wy
                ws[OFF_BOXW + (size_t)bn * 80 + i] = val;
            }
        }
    }
    grid.sync();

    // ---- Phase 2: partial[b][kc][dt][n][dd] = sum_{k in chunk} v[b,n,k] * feats[b,k,d]  (plain stores) ----
    {
        const int b = bid >> 7;
        const int rest = bid & 127;
        const int kc = rest >> 2;
        const int dt = rest & 3;
        const int k0 = kc * KCHUNK;
        float* sw = smem;                    // N_*80 = 2560
        float* vlds = smem + N_ * 80;        // KCHUNK*N_ = 1600

        for (int i = t; i < N_ * 80; i += 256)
            sw[i] = ws[OFF_BOXW + (size_t)b * N_ * 80 + i];
        __syncthreads();
        const float* ifn = ws + OFF_IFN + (size_t)b * K_;
        for (int i = t; i < KCHUNK * N_; i += 256) {
            int kk = i >> 5, n = i & 31;
            int k = k0 + kk;
            int pq = k / P_;
            int q = k - pq * P_;
            vlds[kk * N_ + n] = sw[n * 80 + pq] * sw[n * 80 + P_ + q] * ifn[k];
        }
        __syncthreads();

        float acc[N_];
        #pragma unroll
        for (int n = 0; n < N_; ++n) acc[n] = 0.f;

        const float* fp = feats + ((size_t)b * K_ + k0) * D_ + dt * 256 + t;
        #pragma unroll
        for (int gi = 0; gi < 5; ++gi) {
            float f[10];
            #pragma unroll
            for (int u = 0; u < 10; ++u) f[u] = fp[(size_t)(gi * 10 + u) * D_];   // 10 loads in flight
            #pragma unroll
            for (int u = 0; u < 10; ++u) {
                const float4* vp = (const float4*)&vlds[(gi * 10 + u) * N_];
                #pragma unroll
                for (int j = 0; j < 8; ++j) {            // broadcast b128 reads
                    float4 v4 = vp[j];
                    acc[4 * j + 0] = fmaf(v4.x, f[u], acc[4 * j + 0]);
                    acc[4 * j + 1] = fmaf(v4.y, f[u], acc[4 * j + 1]);
                    acc[4 * j + 2] = fmaf(v4.z, f[u], acc[4 * j + 2]);
                    acc[4 * j + 3] = fmaf(v4.w, f[u], acc[4 * j + 3]);
                }
            }
        }
        float* gp = ws + OFF_GP + ((((size_t)b * KC_ + kc) * 4 + dt) * N_) * 256 + t;
        #pragma unroll
        for (int n = 0; n < N_; ++n) gp[(size_t)n * 256] = acc[n];   // private region, coalesced
    }
    grid.sync();

    // ---- Phase 2.5: g[bn][d] = sum_kc partial  (1 element per thread, 65536 threads) ----
    {
        const int e = bid * 256 + t;                 // = bn*1024 + d
        const int bn = e >> 10, d = e & 1023;
        const int b2 = bn >> 5, n2 = bn & 31, dt2 = d >> 8, dd = d & 255;
        const float* src = ws + OFF_GP + ((size_t)((b2 * 128 + dt2) * 32 + n2)) * 256 + dd;
        float s = 0.f;
        #pragma unroll
        for (int kc = 0; kc < KC_; ++kc) s += src[(size_t)kc * 32768];
        ws[OFF_G + e] = s;
    }
    grid.sync();

    // ---- Phase 3: out[bn][c] = ien[c] * <g[bn,:], emb[c,:]> ----
    {
        const int bng = bid >> 4;
        const int ct = bid & 15;
        float4* g4sh = (float4*)smem;                // 4 rows x 256 float4 = 16 KB
        float* part = smem + 4096;                   // [c_local*4 + bn], 64 floats
        const float* g = ws + OFF_G;
        #pragma unroll
        for (int bn = 0; bn < 4; ++bn)
            g4sh[bn * 256 + t] = ((const float4*)(g + (size_t)(bng * 4 + bn) * D_))[t];
        __syncthreads();

        float p[4][4];
        #pragma unroll
        for (int cc = 0; cc < 4; ++cc)
            #pragma unroll
            for (int bn = 0; bn < 4; ++bn) p[cc][bn] = 0.f;

        #pragma unroll
        for (int i = 0; i < 4; ++i) {
            float4 gv[4];
            #pragma unroll
            for (int bn = 0; bn < 4; ++bn) gv[bn] = g4sh[bn * 256 + lane + 64 * i];
            #pragma unroll
            for (int cc = 0; cc < 4; ++cc) {
                const int c = ct * 16 + wv * 4 + cc;
                float4 e4 = ((const float4*)(emb + (size_t)c * D_))[lane + 64 * i];
                #pragma unroll
                for (int bn = 0; bn < 4; ++bn)
                    p[cc][bn] += e4.x * gv[bn].x + e4.y * gv[bn].y + e4.z * gv[bn].z + e4.w * gv[bn].w;
            }
        }
        #pragma unroll
        for (int cc = 0; cc < 4; ++cc) {
            #pragma unroll
            for (int bn = 0; bn < 4; ++bn) {
                float v = p[cc][bn];
                #pragma unroll
                for (int off = 32; off > 0; off >>= 1) v += __shfl_down(v, off, 64);
                if (lane == 0) part[(wv * 4 + cc) * 4 + bn] = v;
            }
        }
        __syncthreads();
        if (t < 64) {
            const int c = t >> 2, bn = t & 3;
            out[(size_t)(bng * 4 + bn) * C_ + ct * 16 + c] = part[c * 4 + bn] * ws[OFF_IEN + ct * 16 + c];
        }
    }
}

extern "C" void kernel_launch(void* const* d_in, const int* in_sizes, int n_in,
                              void* d_out, int out_size, void* d_ws, size_t ws_size,
                              hipStream_t stream) {
    const float* feats = (const float*)d_in[0];
    const float* emb   = (const float*)d_in[1];
    const int*   boxes = (const int*)d_in[2];
    float* out = (float*)d_out;
    float* ws  = (float*)d_ws;

    void* args[] = {(void*)&feats, (void*)&emb, (void*)&boxes, (void*)&ws, (void*)&out};
    hipLaunchCooperativeKernel(fused, dim3(256), dim3(256), args, 0, stream);
}

// Round 2
// 88.869 us; speedup vs baseline: 2.1056x; 2.1056x over previous
//
#include <hip/hip_runtime.h>
#include <math.h>

// Problem constants
#define TGT 560
#define B_ 2
#define K_ 1600
#define D_ 1024
#define C_ 256
#define N_ 32
#define P_ 40
#define KC_ 64      // k-chunks in kB
#define KCHUNK 25   // K_/KC_

// ws layout (float offsets)
#define OFF_IFN ((size_t)0)                      // B*K = 3200 inverse feat norms
#define OFF_IEN (OFF_IFN + (size_t)B_ * K_)      // C = 256 inverse emb norms
#define OFF_BOXW (OFF_IEN + (size_t)C_)          // B*N*80 (wy*invcnt | wx)
#define OFF_G   ((size_t)16384)                  // B*N*D = 65536 floats (reduced g)
#define OFF_GP  (OFF_G + (size_t)B_ * N_ * D_)   // partials [b][kc][dt][n][256] = 4M floats (16 MB)

// ---- Kernel A: inverse row norms (feats+emb) + per-box separable bicubic weights ----
__global__ __launch_bounds__(256) void kA(const float* __restrict__ feats,
                                          const float* __restrict__ emb,
                                          const int* __restrict__ boxes,
                                          float* __restrict__ ws) {
    __shared__ float shm[80];
    const int r = blockIdx.x;
    const int t = threadIdx.x;
    if (r < B_ * K_ + C_) {
        // ---- row norm block: one block per row, 256 threads x float4 = 4 KB ----
        const float* src;
        float* dst;
        if (r < B_ * K_) { src = feats + (size_t)r * D_; dst = ws + OFF_IFN + r; }
        else             { src = emb + (size_t)(r - B_ * K_) * D_; dst = ws + OFF_IEN + (r - B_ * K_); }
        float4 v = ((const float4*)src)[t];
        float s = v.x * v.x + v.y * v.y + v.z * v.z + v.w * v.w;
        #pragma unroll
        for (int off = 32; off > 0; off >>= 1) s += __shfl_down(s, off, 64);
        if ((t & 63) == 0) shm[t >> 6] = s;
        __syncthreads();
        if (t == 0) {
            float tot = shm[0] + shm[1] + shm[2] + shm[3];
            *dst = 1.0f / sqrtf(tot);   // eps fold: rel err ~1e-11, negligible
        }
    } else {
        // ---- box-weight block (one per bn) ----
        const int bn = r - (B_ * K_ + C_);
        if (t < 80) shm[t] = 0.f;
        __syncthreads();
        const int* bx = boxes + bn * 4;
        const int xmin = bx[0], ymin = bx[1], xmax = bx[2], ymax = bx[3];
        const float invcnt = 1.0f / ((float)(ymax - 1 - ymin) * (float)(xmax - 1 - xmin));
        const int axis = t >> 7;                       // 0 -> y, 1 -> x
        const int rr = t & 127;
        const int lo = (axis ? xmin : ymin);
        const int hi = (axis ? xmax : ymax) - 2;       // inclusive
        for (int h = lo + rr; h <= hi; h += 128) {
            float sf = ((float)h + 0.5f) * (1.0f / 14.0f) - 0.5f;
            int jf = (int)floorf(sf);
            float w[4];
            float norm = 0.f;
            #pragma unroll
            for (int dj = -1; dj <= 2; ++dj) {
                int j = jf + dj;
                float x = fabsf(sf - (float)j);
                float wv = ((1.5f * x - 2.5f) * x) * x + 1.f;            // |x|<1 (Keys a=-0.5)
                if (x >= 1.f) wv = ((-0.5f * x + 2.5f) * x - 4.f) * x + 2.f; // 1<=|x|<2
                if (x >= 2.f) wv = 0.f;
                if (j < 0 || j >= P_) wv = 0.f;        // edge: tap outside -> renorm below
                w[dj + 1] = wv;
                norm += wv;
            }
            float inv = 1.0f / norm;
            #pragma unroll
            for (int dj = 0; dj < 4; ++dj) {
                int j = jf - 1 + dj;
                if (w[dj] != 0.f) atomicAdd(&shm[axis * P_ + j], w[dj] * inv);
            }
        }
        __syncthreads();
        if (t < 80) {
            float val = shm[t];
            if (t < P_) val *= invcnt;                 // fold 1/count into wy
            ws[OFF_BOXW + (size_t)bn * 80 + t] = val;
        }
    }
}

// ---- Kernel B: partial[b][kc][dt][n][dd] = sum_{k in chunk} v[b,n,k]*feats[b,k,d] (plain stores) ----
// 512 blocks (2/CU, 8 waves/CU): b(2) x kc(64) x dt(4). No atomics, no g zero-init.
__global__ __launch_bounds__(256) void kB(const float* __restrict__ feats,
                                          const float* __restrict__ ws,
                                          float* __restrict__ gp_base) {
    __shared__ float sw[N_ * 80];
    __shared__ float vlds[KCHUNK * N_];
    const int bid = blockIdx.x;          // b(2) x kc(64) x dt(4)
    const int b = bid >> 8;
    const int rest = bid & 255;
    const int kc = rest >> 2;
    const int dt = rest & 3;
    const int t = threadIdx.x;
    const int k0 = kc * KCHUNK;

    for (int i = t; i < N_ * 80; i += 256)
        sw[i] = ws[OFF_BOXW + (size_t)b * N_ * 80 + i];
    __syncthreads();
    const float* ifn = ws + OFF_IFN + (size_t)b * K_;
    for (int i = t; i < KCHUNK * N_; i += 256) {
        int kk = i >> 5, n = i & 31;
        int k = k0 + kk;
        int pq = k / P_;
        int q = k - pq * P_;
        vlds[kk * N_ + n] = sw[n * 80 + pq] * sw[n * 80 + P_ + q] * ifn[k];
    }
    __syncthreads();

    float acc[N_];
    #pragma unroll
    for (int n = 0; n < N_; ++n) acc[n] = 0.f;

    const float* fp = feats + ((size_t)b * K_ + k0) * D_ + dt * 256 + t;
    #pragma unroll
    for (int gi = 0; gi < 5; ++gi) {
        float f[5];
        #pragma unroll
        for (int u = 0; u < 5; ++u) f[u] = fp[(size_t)(gi * 5 + u) * D_];  // 5 loads in flight
        #pragma unroll
        for (int u = 0; u < 5; ++u) {
            const float4* vp = (const float4*)&vlds[(gi * 5 + u) * N_];
            #pragma unroll
            for (int j = 0; j < 8; ++j) {            // broadcast b128 reads
                float4 v4 = vp[j];
                acc[4 * j + 0] = fmaf(v4.x, f[u], acc[4 * j + 0]);
                acc[4 * j + 1] = fmaf(v4.y, f[u], acc[4 * j + 1]);
                acc[4 * j + 2] = fmaf(v4.z, f[u], acc[4 * j + 2]);
                acc[4 * j + 3] = fmaf(v4.w, f[u], acc[4 * j + 3]);
            }
        }
    }
    // private coalesced region: [b][kc][dt][n][256], 32 KB contiguous per block
    float* gp = gp_base + ((((size_t)b * KC_ + kc) * 4 + dt) * N_) * 256 + t;
    #pragma unroll
    for (int n = 0; n < N_; ++n) gp[(size_t)n * 256] = acc[n];
}

// ---- Kernel R: g[bn][d] = sum_kc partial (1 elem/thread, 65536 threads, coalesced) ----
__global__ __launch_bounds__(256) void kR(const float* __restrict__ gp_base,
                                          float* __restrict__ g) {
    const int e = blockIdx.x * 256 + threadIdx.x;  // = bn*1024 + d
    const int bn = e >> 10, d = e & 1023;
    const int b2 = bn >> 5, n2 = bn & 31, dt2 = d >> 8, dd = d & 255;
    const float* src = gp_base + (((size_t)(b2 * KC_) * 4 + dt2) * N_ + n2) * 256 + dd;
    float s = 0.f;
    #pragma unroll 16
    for (int kc = 0; kc < KC_; ++kc) s += src[(size_t)kc * (4 * N_ * 256)];
    g[e] = s;
}

// ---- Kernel C: out[bn][c] = ien[c] * <g[bn,:], emb[c,:]> ----
// 256 blocks: bng(16, 4 bn rows) x ct(16, 16 emb rows). Each wave owns 4 distinct c rows.
__global__ __launch_bounds__(256) void kC(const float* __restrict__ emb,
                                          const float* __restrict__ g,
                                          const float* __restrict__ ien,
                                          float* __restrict__ out) {
    __shared__ float4 g4sh[4][D_ / 4];   // 16 KB: 4 box rows
    __shared__ float part[16][4];        // [c_local][bn]
    const int bid = blockIdx.x;
    const int bng = bid >> 4;
    const int ct  = bid & 15;
    const int t = threadIdx.x;
    const int lane = t & 63;
    const int wv = t >> 6;

    #pragma unroll
    for (int bn = 0; bn < 4; ++bn)
        g4sh[bn][t] = ((const float4*)(g + (size_t)(bng * 4 + bn) * D_))[t];
    __syncthreads();

    float p[4][4];                       // [cc][bn]
    #pragma unroll
    for (int cc = 0; cc < 4; ++cc)
        #pragma unroll
        for (int bn = 0; bn < 4; ++bn) p[cc][bn] = 0.f;

    #pragma unroll
    for (int i = 0; i < 4; ++i) {
        float4 gv[4];
        #pragma unroll
        for (int bn = 0; bn < 4; ++bn) gv[bn] = g4sh[bn][lane + 64 * i];
        #pragma unroll
        for (int cc = 0; cc < 4; ++cc) {
            const int c = ct * 16 + wv * 4 + cc;
            float4 e = ((const float4*)(emb + (size_t)c * D_))[lane + 64 * i];
            #pragma unroll
            for (int bn = 0; bn < 4; ++bn)
                p[cc][bn] += e.x * gv[bn].x + e.y * gv[bn].y + e.z * gv[bn].z + e.w * gv[bn].w;
        }
    }
    #pragma unroll
    for (int cc = 0; cc < 4; ++cc) {
        #pragma unroll
        for (int bn = 0; bn < 4; ++bn) {
            float v = p[cc][bn];
            #pragma unroll
            for (int off = 32; off > 0; off >>= 1) v += __shfl_down(v, off, 64);
            if (lane == 0) part[wv * 4 + cc][bn] = v;
        }
    }
    __syncthreads();
    if (t < 64) {
        const int c = t >> 2, bn = t & 3;
        out[(size_t)(bng * 4 + bn) * C_ + ct * 16 + c] = part[c][bn] * ien[ct * 16 + c];
    }
}

extern "C" void kernel_launch(void* const* d_in, const int* in_sizes, int n_in,
                              void* d_out, int out_size, void* d_ws, size_t ws_size,
                              hipStream_t stream) {
    const float* feats = (const float*)d_in[0];
    const float* emb   = (const float*)d_in[1];
    const int*   boxes = (const int*)d_in[2];
    float* out = (float*)d_out;
    float* ws  = (float*)d_ws;

    kA<<<B_ * K_ + C_ + B_ * N_, 256, 0, stream>>>(feats, emb, boxes, ws);
    kB<<<B_ * KC_ * 4, 256, 0, stream>>>(feats, ws, ws + OFF_GP);
    kR<<<256, 256, 0, stream>>>(ws + OFF_GP, ws + OFF_G);
    kC<<<256, 256, 0, stream>>>(emb, ws + OFF_G, ws + OFF_IEN, out);
}